// Round 8
// baseline (98.191 us; speedup 1.0000x reference)
//
#include <hip/hip_runtime.h>

#define Q 4096
#define L 8192
#define NCB 2048               // ctx blocks in K1 (was 1024)
#define RPB (L / NCB)          // 4 rows per ctx block (was 8)
#define NOB 256                // out1 blocks in K1 (4 waves each, 4 rows/wave)

// ---------------------------------------------------------------------------
// K1a (blocks 0..NCB-1): online softmax-weighted sum over RPB ctx rows.
//   q in LDS; next row prefetched into a second register buffer while the
//   current row goes through reduce/barrier/accumulate; sred double-buffered
//   (one barrier per row).  RPB=4 doubles block-parallelism vs round 6:
//   grid 2304 blocks ~ 8-9 blocks/CU (R6 measured 35.5% occupancy at 5/CU).
// K1b (blocks NCB..NCB+NOB-1): out1[i] = Kw[i, 0:Q] . q (unchanged).
// ---------------------------------------------------------------------------
__global__ __launch_bounds__(256) void k1_kernel(
    const float* __restrict__ qvec, const float* __restrict__ ctx,
    const float* __restrict__ Kw,
    float* __restrict__ partial, float* __restrict__ m_arr,
    float* __restrict__ Z_arr, float* __restrict__ out1)
{
    __shared__ float4 qs4[Q / 4];      // 16 KB staged query
    __shared__ float sred[2][4];
    const int tid  = threadIdx.x;
    const int lane = tid & 63;
    const int wid  = tid >> 6;

    if (blockIdx.x < NCB) {
        const float4* __restrict__ qg = (const float4*)qvec;
        const float4* __restrict__ cb = (const float4*)ctx;
        const size_t base = (size_t)blockIdx.x * RPB * (Q / 4);

        // stage q into LDS (one barrier)
        #pragma unroll
        for (int k = 0; k < 4; ++k) qs4[tid + k * 256] = qg[tid + k * 256];
        __syncthreads();

        float4 va[4], vb[4];
        #pragma unroll
        for (int k = 0; k < 4; ++k) va[k] = cb[base + tid + k * 256];

        float4 acc[4];
        #pragma unroll
        for (int k = 0; k < 4; ++k) acc[k] = make_float4(0.f, 0.f, 0.f, 0.f);
        float m = -3.4e38f, Z = 0.f;

        // process(v, r): dot vs LDS q, 1-barrier reduce, online update
        #define PROCESS(V, R)                                                  \
        {                                                                      \
            float d = 0.f;                                                     \
            _Pragma("unroll")                                                  \
            for (int k = 0; k < 4; ++k) {                                      \
                const float4 qk = qs4[tid + k * 256];                          \
                d = fmaf((V)[k].x, qk.x, d); d = fmaf((V)[k].y, qk.y, d);      \
                d = fmaf((V)[k].z, qk.z, d); d = fmaf((V)[k].w, qk.w, d);      \
            }                                                                  \
            _Pragma("unroll")                                                  \
            for (int off = 32; off > 0; off >>= 1)                             \
                d += __shfl_down(d, off, 64);                                  \
            if (lane == 0) sred[(R) & 1][wid] = d;                             \
            __syncthreads();                                                   \
            const float s = sred[(R) & 1][0] + sred[(R) & 1][1] +              \
                            sred[(R) & 1][2] + sred[(R) & 1][3];               \
            if (s > m) {                                                       \
                const float sc = __expf(m - s);                                \
                Z *= sc;                                                       \
                _Pragma("unroll")                                              \
                for (int k = 0; k < 4; ++k) {                                  \
                    acc[k].x *= sc; acc[k].y *= sc;                            \
                    acc[k].z *= sc; acc[k].w *= sc;                            \
                }                                                              \
                m = s;                                                         \
            }                                                                  \
            const float w = __expf(s - m);                                     \
            Z += w;                                                            \
            _Pragma("unroll")                                                  \
            for (int k = 0; k < 4; ++k) {                                      \
                acc[k].x = fmaf(w, (V)[k].x, acc[k].x);                        \
                acc[k].y = fmaf(w, (V)[k].y, acc[k].y);                        \
                acc[k].z = fmaf(w, (V)[k].z, acc[k].z);                        \
                acc[k].w = fmaf(w, (V)[k].w, acc[k].w);                        \
            }                                                                  \
        }

        #pragma unroll
        for (int rp = 0; rp < RPB; rp += 2) {
            // prefetch row rp+1 while processing rp (in va)
            #pragma unroll
            for (int k = 0; k < 4; ++k)
                vb[k] = cb[base + (size_t)(rp + 1) * (Q / 4) + tid + k * 256];
            PROCESS(va, rp)
            // prefetch row rp+2 while processing rp+1 (in vb)
            if (rp + 2 < RPB) {
                #pragma unroll
                for (int k = 0; k < 4; ++k)
                    va[k] = cb[base + (size_t)(rp + 2) * (Q / 4) + tid + k * 256];
            }
            PROCESS(vb, rp + 1)
        }
        #undef PROCESS

        float4* __restrict__ pb = (float4*)(partial + (size_t)blockIdx.x * Q);
        #pragma unroll
        for (int k = 0; k < 4; ++k) pb[tid + k * 256] = acc[k];
        if (tid == 0) { m_arr[blockIdx.x] = m; Z_arr[blockIdx.x] = Z; }
    } else {
        // ---- out1 = Kw[:, 0:Q] . q, one wave per row, 4 rows per wave ----
        const int b = blockIdx.x - NCB;
        const float4* __restrict__ qv = (const float4*)qvec;
        for (int rr = 0; rr < 4; ++rr) {
            const int i = (b * 4 + wid) + rr * 1024;
            const float4* __restrict__ row = (const float4*)(Kw + (size_t)i * (2 * Q));
            float a = 0.f;
            #pragma unroll 4
            for (int it = 0; it < 16; ++it) {
                const int idx = it * 64 + lane;
                float4 x = row[idx], y = qv[idx];
                a = fmaf(x.x, y.x, a); a = fmaf(x.y, y.y, a);
                a = fmaf(x.z, y.z, a); a = fmaf(x.w, y.w, a);
            }
            #pragma unroll
            for (int off = 32; off > 0; off >>= 1) a += __shfl_down(a, off, 64);
            if (lane == 0) out1[i] = a;
        }
    }
}

// ---------------------------------------------------------------------------
// K2: merge the NCB partials:  s_t[j] = (1/Z_tot) * sum_b exp(m_b - M) * p_b[j]
//     64 blocks; each block owns 16 float4 columns; 16 b-groups sweep NCB.
// ---------------------------------------------------------------------------
__global__ __launch_bounds__(256) void k2_kernel(
    const float* __restrict__ partial, const float* __restrict__ m_arr,
    const float* __restrict__ Z_arr, float* __restrict__ s_t)
{
    __shared__ float w_s[NCB];          // 8 KB
    __shared__ float redm[4];
    __shared__ float4 sacc[16][16];     // 4 KB
    const int tid  = threadIdx.x;
    const int lane = tid & 63;
    const int wid  = tid >> 6;

    // M = max_b m_b
    float lm = -3.4e38f;
    for (int b = tid; b < NCB; b += 256) lm = fmaxf(lm, m_arr[b]);
    #pragma unroll
    for (int off = 32; off > 0; off >>= 1) lm = fmaxf(lm, __shfl_down(lm, off, 64));
    if (lane == 0) redm[wid] = lm;
    __syncthreads();
    const float M = fmaxf(fmaxf(redm[0], redm[1]), fmaxf(redm[2], redm[3]));
    __syncthreads();

    // w_b and Z_tot
    float lz = 0.f;
    for (int b = tid; b < NCB; b += 256) {
        const float w = __expf(m_arr[b] - M);
        w_s[b] = w;
        lz = fmaf(w, Z_arr[b], lz);
    }
    #pragma unroll
    for (int off = 32; off > 0; off >>= 1) lz += __shfl_down(lz, off, 64);
    if (lane == 0) redm[wid] = lz;
    __syncthreads();
    const float invZ = 1.f / (redm[0] + redm[1] + redm[2] + redm[3]);

    // weighted column sums
    const int cidx = tid & 15;               // column within block
    const int g    = tid >> 4;               // 0..15 b-group
    const int c4   = blockIdx.x * 16 + cidx; // global float4 column
    const float4* __restrict__ p = (const float4*)partial;
    float4 acc = make_float4(0.f, 0.f, 0.f, 0.f);
    for (int b = g; b < NCB; b += 16) {
        const float w = w_s[b];
        float4 v = p[(size_t)b * (Q / 4) + c4];
        acc.x = fmaf(w, v.x, acc.x); acc.y = fmaf(w, v.y, acc.y);
        acc.z = fmaf(w, v.z, acc.z); acc.w = fmaf(w, v.w, acc.w);
    }
    sacc[g][cidx] = acc;
    __syncthreads();
    if (g == 0) {
        float4 t = sacc[0][cidx];
        #pragma unroll
        for (int gg = 1; gg < 16; ++gg) {
            float4 u = sacc[gg][cidx];
            t.x += u.x; t.y += u.y; t.z += u.z; t.w += u.w;
        }
        t.x *= invZ; t.y *= invZ; t.z *= invZ; t.w *= invZ;
        ((float4*)s_t)[c4] = t;
    }
}

// ---------------------------------------------------------------------------
// K3: out[i] = out1[i] + Kw[i, Q:2Q] . s_t    (one wave per row)
// ---------------------------------------------------------------------------
__global__ __launch_bounds__(256) void k3_kernel(
    const float* __restrict__ Kw, const float* __restrict__ s_t,
    const float* __restrict__ out1, float* __restrict__ out)
{
    const int lane = threadIdx.x & 63;
    const int wid  = threadIdx.x >> 6;
    const int i = blockIdx.x * 4 + wid;
    const float4* __restrict__ row = (const float4*)(Kw + (size_t)i * (2 * Q) + Q);
    const float4* __restrict__ sv  = (const float4*)s_t;
    float a = 0.f;
    #pragma unroll 4
    for (int it = 0; it < 16; ++it) {
        const int idx = it * 64 + lane;
        float4 x = row[idx], y = sv[idx];
        a = fmaf(x.x, y.x, a); a = fmaf(x.y, y.y, a);
        a = fmaf(x.z, y.z, a); a = fmaf(x.w, y.w, a);
    }
    #pragma unroll
    for (int off = 32; off > 0; off >>= 1) a += __shfl_down(a, off, 64);
    if (lane == 0) out[i] = out1[i] + a;
}

// ---------------------------------------------------------------------------
extern "C" void kernel_launch(void* const* d_in, const int* in_sizes, int n_in,
                              void* d_out, int out_size, void* d_ws, size_t ws_size,
                              hipStream_t stream)
{
    const float* query = (const float*)d_in[0];   // [Q]
    const float* ctx   = (const float*)d_in[1];   // [L, Q]
    const float* Kw    = (const float*)d_in[2];   // [Q, 2Q]
    float* out = (float*)d_out;                   // [Q]

    // workspace layout (floats)
    float* ws      = (float*)d_ws;
    float* m_arr   = ws;                          // NCB   = 2048
    float* Z_arr   = ws + NCB;                    // NCB   = 2048
    float* out1    = ws + 2 * NCB;                // Q     = 4096
    float* s_t     = ws + 2 * NCB + Q;            // Q     = 4096
    float* partial = ws + 2 * NCB + 2 * Q;        // NCB*Q = 32 MiB

    k1_kernel<<<NCB + NOB, 256, 0, stream>>>(query, ctx, Kw,
                                             partial, m_arr, Z_arr, out1);
    k2_kernel<<<Q / 4 / 16, 256, 0, stream>>>(partial, m_arr, Z_arr, s_t);
    k3_kernel<<<Q / 4, 256, 0, stream>>>(Kw, s_t, out1, out);
}

// Round 9
// 79.865 us; speedup vs baseline: 1.2295x; 1.2295x over previous
//
#include <hip/hip_runtime.h>

#define Q 4096
#define L 8192

// ---------------------------------------------------------------------------
// K1: two interleaved streaming families (blockIdx % 3):
//   fam 0,1 -> score[l] = ctx[l].q          (8192 blocks, block-per-row)
//   fam 2   -> out1[i]  = Kw[i,0:Q].q       (4096 blocks, block-per-row)
// Pure R1-style streaming: 4 float4 loads/thread, shfl+LDS reduce, no inner
// barriers. 12288 blocks total.
// ---------------------------------------------------------------------------
__global__ __launch_bounds__(256) void k1_kernel(
    const float* __restrict__ qvec, const float* __restrict__ ctx,
    const float* __restrict__ Kw, float* __restrict__ score,
    float* __restrict__ out1)
{
    const int b   = blockIdx.x;
    const int fam = b % 3;
    const int g   = b / 3;                 // 0..4095
    const int tid  = threadIdx.x;
    const int lane = tid & 63;
    const int wid  = tid >> 6;

    const float4* __restrict__ row;
    float* outp;
    if (fam < 2) {
        const int l = g * 2 + fam;         // 0..8191
        row  = (const float4*)(ctx + (size_t)l * Q);
        outp = score + l;
    } else {
        row  = (const float4*)(Kw + (size_t)g * (2 * Q));
        outp = out1 + g;
    }

    const float4* __restrict__ qv = (const float4*)qvec;
    float acc = 0.f;
    #pragma unroll
    for (int i = tid; i < Q / 4; i += 256) {
        float4 a = row[i];
        float4 c = qv[i];
        acc = fmaf(a.x, c.x, acc);
        acc = fmaf(a.y, c.y, acc);
        acc = fmaf(a.z, c.z, acc);
        acc = fmaf(a.w, c.w, acc);
    }
    #pragma unroll
    for (int off = 32; off > 0; off >>= 1) acc += __shfl_down(acc, off, 64);

    __shared__ float red[4];
    if (lane == 0) red[wid] = acc;
    __syncthreads();
    if (tid == 0) *outp = red[0] + red[1] + red[2] + red[3];
}

// ---------------------------------------------------------------------------
// K2: att = softmax(score). Single block (proven in R1).
// ---------------------------------------------------------------------------
__global__ __launch_bounds__(1024) void softmax_kernel(
    const float* __restrict__ score, float* __restrict__ att)
{
    __shared__ float redm[16];
    __shared__ float reds[16];
    const int tid  = threadIdx.x;
    const int lane = tid & 63;
    const int wid  = tid >> 6;

    float m = -3.4e38f;
    for (int i = tid; i < L; i += 1024) m = fmaxf(m, score[i]);
    #pragma unroll
    for (int off = 32; off > 0; off >>= 1) m = fmaxf(m, __shfl_down(m, off, 64));
    if (lane == 0) redm[wid] = m;
    __syncthreads();
    float M = redm[0];
    #pragma unroll
    for (int w = 1; w < 16; ++w) M = fmaxf(M, redm[w]);

    float s = 0.f;
    for (int i = tid; i < L; i += 1024) s += __expf(score[i] - M);
    #pragma unroll
    for (int off = 32; off > 0; off >>= 1) s += __shfl_down(s, off, 64);
    if (lane == 0) reds[wid] = s;
    __syncthreads();
    float Z = 0.f;
    #pragma unroll
    for (int w = 0; w < 16; ++w) Z += reds[w];
    const float inv = 1.0f / Z;

    for (int i = tid; i < L; i += 1024) att[i] = __expf(score[i] - M) * inv;
}

// ---------------------------------------------------------------------------
// K3: weighted sum partials (ctx is L3-resident after K1).
//   512 blocks = 8 col-chunks (128 float4 cols) x 64 row-chunks (128 rows).
//   Thread owns one float4 column over 64 rows; barrier only after att stage.
// ---------------------------------------------------------------------------
__global__ __launch_bounds__(256) void wsum_kernel(
    const float* __restrict__ ctx, const float* __restrict__ att,
    float* __restrict__ partial)
{
    __shared__ float att_s[128];
    const int cc = blockIdx.x & 7;         // col chunk
    const int rc = blockIdx.x >> 3;        // row chunk (0..63)
    const int tid = threadIdx.x;
    const int rg  = tid >> 7;              // 0..1 row-group (64 rows each)
    const int col = cc * 128 + (tid & 127);

    if (tid < 128) att_s[tid] = att[rc * 128 + tid];
    __syncthreads();

    const float4* __restrict__ cb = (const float4*)ctx;
    const int r0 = rc * 128 + rg * 64;
    float4 acc = make_float4(0.f, 0.f, 0.f, 0.f);
    #pragma unroll 8
    for (int r = 0; r < 64; ++r) {
        const float a = att_s[rg * 64 + r];
        float4 v = cb[(size_t)(r0 + r) * (Q / 4) + col];
        acc.x = fmaf(a, v.x, acc.x);
        acc.y = fmaf(a, v.y, acc.y);
        acc.z = fmaf(a, v.z, acc.z);
        acc.w = fmaf(a, v.w, acc.w);
    }
    ((float4*)partial)[(size_t)(rc * 2 + rg) * (Q / 4) + col] = acc;
}

// ---------------------------------------------------------------------------
// K4: s_t[j] = sum over 128 partial rows. 4 blocks x 256 threads.
// ---------------------------------------------------------------------------
__global__ __launch_bounds__(256) void reduce_kernel(
    const float* __restrict__ partial, float* __restrict__ s_t)
{
    const int c4 = blockIdx.x * 256 + threadIdx.x;   // float4 column
    const float4* __restrict__ p = (const float4*)partial;
    float4 acc = make_float4(0.f, 0.f, 0.f, 0.f);
    #pragma unroll 8
    for (int b = 0; b < 128; ++b) {
        float4 v = p[(size_t)b * (Q / 4) + c4];
        acc.x += v.x; acc.y += v.y; acc.z += v.z; acc.w += v.w;
    }
    ((float4*)s_t)[c4] = acc;
}

// ---------------------------------------------------------------------------
// K5: out[i] = out1[i] + Kw[i, Q:2Q] . s_t. Block-per-row (4096 blocks).
// ---------------------------------------------------------------------------
__global__ __launch_bounds__(256) void k5_kernel(
    const float* __restrict__ Kw, const float* __restrict__ s_t,
    const float* __restrict__ out1, float* __restrict__ out)
{
    const int i = blockIdx.x;
    const int tid  = threadIdx.x;
    const int lane = tid & 63;
    const int wid  = tid >> 6;
    const float4* __restrict__ row = (const float4*)(Kw + (size_t)i * (2 * Q) + Q);
    const float4* __restrict__ sv  = (const float4*)s_t;

    float acc = 0.f;
    #pragma unroll
    for (int j = tid; j < Q / 4; j += 256) {
        float4 a = row[j];
        float4 c = sv[j];
        acc = fmaf(a.x, c.x, acc);
        acc = fmaf(a.y, c.y, acc);
        acc = fmaf(a.z, c.z, acc);
        acc = fmaf(a.w, c.w, acc);
    }
    #pragma unroll
    for (int off = 32; off > 0; off >>= 1) acc += __shfl_down(acc, off, 64);

    __shared__ float red[4];
    if (lane == 0) red[wid] = acc;
    __syncthreads();
    if (tid == 0) out[i] = out1[i] + red[0] + red[1] + red[2] + red[3];
}

// ---------------------------------------------------------------------------
extern "C" void kernel_launch(void* const* d_in, const int* in_sizes, int n_in,
                              void* d_out, int out_size, void* d_ws, size_t ws_size,
                              hipStream_t stream)
{
    const float* query = (const float*)d_in[0];   // [Q]
    const float* ctx   = (const float*)d_in[1];   // [L, Q]
    const float* Kw    = (const float*)d_in[2];   // [Q, 2Q]
    float* out = (float*)d_out;                   // [Q]

    // workspace layout (floats)
    float* ws      = (float*)d_ws;
    float* score   = ws;                          // 8192
    float* att     = ws + L;                      // 8192
    float* out1    = ws + 2 * L;                  // 4096
    float* s_t     = ws + 2 * L + Q;              // 4096
    float* partial = ws + 2 * L + 2 * Q;          // 128*4096 = 2 MiB

    k1_kernel<<<12288, 256, 0, stream>>>(query, ctx, Kw, score, out1);
    softmax_kernel<<<1, 1024, 0, stream>>>(score, att);
    wsum_kernel<<<512, 256, 0, stream>>>(ctx, att, partial);
    reduce_kernel<<<4, 256, 0, stream>>>(partial, s_t);
    k5_kernel<<<Q, 256, 0, stream>>>(Kw, s_t, out1, out);
}